// Round 1
// baseline (237.321 us; speedup 1.0000x reference)
//
#include <hip/hip_runtime.h>

#define NB 4
#define NS 4096
#define NDIN 1024
#define ND 64

typedef __attribute__((ext_vector_type(4))) float f32x4;
typedef __attribute__((ext_vector_type(8))) short s16x8;
typedef __attribute__((ext_vector_type(4))) short s16x4;

__device__ __forceinline__ unsigned short f2bf(float f) {
  union { float f; unsigned u; } x; x.f = f;
  unsigned r = x.u + 0x7fffu + ((x.u >> 16) & 1u);
  return (unsigned short)(r >> 16);
}

// ---- kernel 0: W -> bf16, transposed to [mat][col][k] for B-fragment reads
__global__ __launch_bounds__(256) void prep_w_kernel(
    const float* __restrict__ Wq, const float* __restrict__ Wk,
    const float* __restrict__ Wv, unsigned short* __restrict__ wt) {
  int idx = blockIdx.x * 256 + threadIdx.x;  // grid sized exactly 3*64*1024
  int m = idx >> 16;
  int r = idx & 65535;
  int c = r >> 10;
  int k = r & 1023;
  const float* W = (m == 0) ? Wq : (m == 1) ? Wk : Wv;
  wt[idx] = f2bf(W[k * ND + c]);
}

// ---- kernel 1: projection X[16384][1024] @ W[1024][64] + b -> bf16
// y==0: q row-major, y==1: k row-major, y==2: v transposed [b][64][4096]
__global__ __launch_bounds__(256) void proj_kernel(
    const float* __restrict__ Xq, const float* __restrict__ Xk, const float* __restrict__ Xv,
    const float* __restrict__ bq, const float* __restrict__ bk, const float* __restrict__ bv,
    const unsigned short* __restrict__ wt_all,
    unsigned short* __restrict__ q_o, unsigned short* __restrict__ k_o,
    unsigned short* __restrict__ vt_o) {
  const int y = blockIdx.y;
  const float* __restrict__ X = (y == 0) ? Xq : (y == 1) ? Xk : Xv;
  const float* __restrict__ bias = (y == 0) ? bq : (y == 1) ? bk : bv;
  const unsigned short* __restrict__ wt = wt_all + y * (ND * NDIN);
  const int row0 = blockIdx.x * 64;
  const int tid = threadIdx.x;
  const int lane = tid & 63;
  const int w = tid >> 6;
  const int ql = lane & 15;
  const int grp = lane >> 4;

  __shared__ unsigned short abuf[64][40];  // 80B row stride: 2-way bank alias (free)

  f32x4 acc[4] = {};

  for (int k0 = 0; k0 < NDIN; k0 += 32) {
    #pragma unroll
    for (int j = 0; j < 2; ++j) {
      int idx = tid + 256 * j;       // 0..511
      int rr = idx >> 3;             // 64 rows
      int c4 = idx & 7;              // 8 float4 per row
      const float4 xv = *reinterpret_cast<const float4*>(
          &X[(size_t)(row0 + rr) * NDIN + k0 + c4 * 4]);
      s16x4 hv;
      hv[0] = (short)f2bf(xv.x);
      hv[1] = (short)f2bf(xv.y);
      hv[2] = (short)f2bf(xv.z);
      hv[3] = (short)f2bf(xv.w);
      *reinterpret_cast<s16x4*>(&abuf[rr][c4 * 4]) = hv;
    }
    __syncthreads();
    const s16x8 a = *reinterpret_cast<const s16x8*>(&abuf[16 * w + ql][grp * 8]);
    #pragma unroll
    for (int nt = 0; nt < 4; ++nt) {
      const s16x8 bfr = *reinterpret_cast<const s16x8*>(
          &wt[(size_t)(ql + 16 * nt) * NDIN + k0 + grp * 8]);
      acc[nt] = __builtin_amdgcn_mfma_f32_16x16x32_bf16(a, bfr, acc[nt], 0, 0, 0);
    }
    __syncthreads();
  }

  const int b = row0 >> 12;
  const int s0 = row0 & 4095;
  #pragma unroll
  for (int nt = 0; nt < 4; ++nt) {
    const int col = ql + 16 * nt;
    const float bia = bias[col];
    #pragma unroll
    for (int r = 0; r < 4; ++r) {
      const int rr = 16 * w + grp * 4 + r;  // C layout: col=lane&15, row=(lane>>4)*4+r
      const unsigned short h = f2bf(acc[nt][r] + bia);
      if (y == 0) {
        q_o[(size_t)(row0 + rr) * ND + col] = h;
      } else if (y == 1) {
        k_o[(size_t)(row0 + rr) * ND + col] = h;
      } else {
        vt_o[(size_t)b * ND * NS + (size_t)col * NS + (s0 + rr)] = h;
      }
    }
  }
}

// ---- kernel 2: flash attention, swapped QK^T, 16 q-rows/block, 4-way kv-split
__global__ __launch_bounds__(256) void attn_kernel(
    const unsigned short* __restrict__ qm, const unsigned short* __restrict__ km,
    const unsigned short* __restrict__ vt, const int* __restrict__ mask,
    float* __restrict__ out) {
  const int b = blockIdx.y;
  const int q0 = blockIdx.x * 16;
  const int tid = threadIdx.x;
  const int lane = tid & 63;
  const int w = tid >> 6;
  const int ql = lane & 15;   // q col (softmax state) / also v col in PV epilogue
  const int grp = lane >> 4;  // 0..3

  __shared__ unsigned short p_lds[4][16][72];  // per-wave P, 144B stride
  __shared__ float Lm[4][16];
  __shared__ float Ll[4][16];
  __shared__ float accbuf[4][16][64];

  // Q as B-operand fragments (held for whole kernel)
  const size_t qrow = (size_t)(b * NS + q0 + ql) * ND;
  const s16x8 qf0 = *reinterpret_cast<const s16x8*>(qm + qrow + grp * 8);
  const s16x8 qf1 = *reinterpret_cast<const s16x8*>(qm + qrow + 32 + grp * 8);

  f32x4 acc_o[4] = {};
  float m_i = -INFINITY;
  float l_i = 0.f;

  const size_t kbase = (size_t)b * NS * ND;
  const size_t vbase = (size_t)b * ND * NS;
  const size_t mbase = (size_t)b * NS * NS + (size_t)(q0 + ql) * NS;

  for (int t = 0; t < 16; ++t) {
    const int kv0 = w * 1024 + t * 64;  // wave-private kv quarter
    float sc[16];
    #pragma unroll
    for (int mt = 0; mt < 4; ++mt) {
      // K as A-operand: scores^T[kv][q]
      const size_t krow = kbase + (size_t)(kv0 + 16 * mt + ql) * ND;
      const s16x8 kf0 = *reinterpret_cast<const s16x8*>(km + krow + grp * 8);
      const s16x8 kf1 = *reinterpret_cast<const s16x8*>(km + krow + 32 + grp * 8);
      f32x4 s4 = {0.f, 0.f, 0.f, 0.f};
      s4 = __builtin_amdgcn_mfma_f32_16x16x32_bf16(kf0, qf0, s4, 0, 0, 0);
      s4 = __builtin_amdgcn_mfma_f32_16x16x32_bf16(kf1, qf1, s4, 0, 0, 0);
      // lane holds kv = 16*mt + grp*4 + r for q = q0+ql ; mask int4 is 16B aligned
      const int4 mv = *reinterpret_cast<const int4*>(mask + mbase + kv0 + 16 * mt + grp * 4);
      sc[4 * mt + 0] = (mv.x != 0) ? s4[0] * 0.125f : -1e30f;
      sc[4 * mt + 1] = (mv.y != 0) ? s4[1] * 0.125f : -1e30f;
      sc[4 * mt + 2] = (mv.z != 0) ? s4[2] * 0.125f : -1e30f;
      sc[4 * mt + 3] = (mv.w != 0) ? s4[3] * 0.125f : -1e30f;
    }
    // column(q)-softmax: values lane-local + 2 shuffles across grp
    float tm = sc[0];
    #pragma unroll
    for (int r = 1; r < 16; ++r) tm = fmaxf(tm, sc[r]);
    tm = fmaxf(tm, __shfl_xor(tm, 16));
    tm = fmaxf(tm, __shfl_xor(tm, 32));
    const float new_m = fmaxf(m_i, tm);
    const float alpha = __expf(m_i - new_m);  // first tile: exp(-inf)=0
    float ssum = 0.f;
    #pragma unroll
    for (int r = 0; r < 16; ++r) {
      sc[r] = __expf(sc[r] - new_m);
      ssum += sc[r];
    }
    ssum += __shfl_xor(ssum, 16);
    ssum += __shfl_xor(ssum, 32);
    l_i = l_i * alpha + ssum;
    m_i = new_m;

    // P -> wave-private LDS as bf16 (A-operand layout [q][kv])
    #pragma unroll
    for (int mt = 0; mt < 4; ++mt) {
      s16x4 pk;
      pk[0] = (short)f2bf(sc[4 * mt + 0]);
      pk[1] = (short)f2bf(sc[4 * mt + 1]);
      pk[2] = (short)f2bf(sc[4 * mt + 2]);
      pk[3] = (short)f2bf(sc[4 * mt + 3]);
      *reinterpret_cast<s16x4*>(&p_lds[w][ql][16 * mt + grp * 4]) = pk;
    }
    asm volatile("s_waitcnt lgkmcnt(0)" ::: "memory");
    __builtin_amdgcn_sched_barrier(0);

    // rescale accumulator: alpha lives at lane (q), out rows are grp*4+r
    #pragma unroll
    for (int r = 0; r < 4; ++r) {
      const float ar = __shfl(alpha, grp * 4 + r);
      acc_o[0][r] *= ar;
      acc_o[1][r] *= ar;
      acc_o[2][r] *= ar;
      acc_o[3][r] *= ar;
    }

    // PV: A = P from LDS, B = V^T from global (L2-resident), contiguous 16B frags
    #pragma unroll
    for (int ks = 0; ks < 2; ++ks) {
      const s16x8 pa = *reinterpret_cast<const s16x8*>(&p_lds[w][ql][ks * 32 + grp * 8]);
      #pragma unroll
      for (int nt = 0; nt < 4; ++nt) {
        const s16x8 vb = *reinterpret_cast<const s16x8*>(
            vt + vbase + (size_t)(ql + 16 * nt) * NS + kv0 + ks * 32 + grp * 8);
        acc_o[nt] = __builtin_amdgcn_mfma_f32_16x16x32_bf16(pa, vb, acc_o[nt], 0, 0, 0);
      }
    }
  }

  // combine the 4 kv-split partials (flash LSE-combine)
  if (lane < 16) {
    Lm[w][lane] = m_i;
    Ll[w][lane] = l_i;
  }
  __syncthreads();

  #pragma unroll
  for (int r = 0; r < 4; ++r) {
    const int qq = grp * 4 + r;
    const float m0 = Lm[0][qq], m1 = Lm[1][qq], m2 = Lm[2][qq], m3 = Lm[3][qq];
    const float M = fmaxf(fmaxf(m0, m1), fmaxf(m2, m3));
    const float denom = Ll[0][qq] * __expf(m0 - M) + Ll[1][qq] * __expf(m1 - M) +
                        Ll[2][qq] * __expf(m2 - M) + Ll[3][qq] * __expf(m3 - M);
    const float f = __expf(Lm[w][qq] - M) / denom;
    #pragma unroll
    for (int nt = 0; nt < 4; ++nt) {
      accbuf[w][qq][ql + 16 * nt] = acc_o[nt][r] * f;
    }
  }
  __syncthreads();

  {
    const int qq = tid >> 4;
    const int v4 = tid & 15;
    f32x4 s = *reinterpret_cast<const f32x4*>(&accbuf[0][qq][v4 * 4]);
    #pragma unroll
    for (int w2 = 1; w2 < 4; ++w2)
      s += *reinterpret_cast<const f32x4*>(&accbuf[w2][qq][v4 * 4]);
    *reinterpret_cast<f32x4*>(&out[(size_t)(b * NS + q0 + qq) * ND + v4 * 4]) = s;
  }
}

extern "C" void kernel_launch(void* const* d_in, const int* in_sizes, int n_in,
                              void* d_out, int out_size, void* d_ws, size_t ws_size,
                              hipStream_t stream) {
  const float* query = (const float*)d_in[0];
  const float* key   = (const float*)d_in[1];
  const float* value = (const float*)d_in[2];
  const int*   mask  = (const int*)d_in[3];
  const float* Wq = (const float*)d_in[4];
  const float* bq = (const float*)d_in[5];
  const float* Wk = (const float*)d_in[6];
  const float* bk = (const float*)d_in[7];
  const float* Wv = (const float*)d_in[8];
  const float* bv = (const float*)d_in[9];
  float* out = (float*)d_out;

  char* ws = (char*)d_ws;
  unsigned short* wt  = (unsigned short*)(ws);                          // 384 KB
  unsigned short* qb  = (unsigned short*)(ws + 393216);                 // 2 MB
  unsigned short* kb  = (unsigned short*)(ws + 393216 + 2097152);       // 2 MB
  unsigned short* vtb = (unsigned short*)(ws + 393216 + 2 * 2097152);   // 2 MB

  prep_w_kernel<<<dim3(768), dim3(256), 0, stream>>>(Wq, Wk, Wv, wt);
  proj_kernel<<<dim3(256, 3), dim3(256), 0, stream>>>(query, key, value,
                                                      bq, bk, bv, wt, qb, kb, vtb);
  attn_kernel<<<dim3(256, NB), dim3(256), 0, stream>>>(qb, kb, vtb, mask, out);
}